// Round 4
// baseline (677.424 us; speedup 1.0000x reference)
//
#include <hip/hip_runtime.h>

// Problem constants: B,S,NODE,DEP,R,L,E = 32,1024,256,64,50,16,128
constexpr int B_ = 32;
constexpr int S_ = 1024;
constexpr int NODE_ = 256;
constexpr int DEP_ = 64;
constexpr int R_ = 50;
constexpr int L_ = 16;
constexpr int E_ = 128;
constexpr int FEAT_ = NODE_ + DEP_;     // 320
constexpr int NEDGE_ = B_ * E_;         // 4096 edges per layer
constexpr int BS_ = B_ * S_;            // 32768 rows
constexpr int CH_ = 16;                 // edges per relation-chunk
constexpr int NCH_ = 320;               // sum ceil(n_r/16) <= 256+50 = 306
constexpr int NSLICE_ = 5;              // 320/64 d-slices (one per wave)
constexpr int PREB_ = 512;              // worker blocks in k_pre (besides 16 bin blocks)

// ---------------------------------------------------------------------------
// Workspace layout (floats unless noted):
//  child[BS*64] | A0 | A1 | A2 (BS*64 each, triple-buffered accumulators) |
//  WT2[R*80*64*4] | sorted[L*NEDGE] (int) | chunks[L*NCH] (int4) |
//  hc[(L+1)*BS] (int; hc[L] = all-zero dummy used as "layer -1")
// Semantics: layer l accumulates into A[l%3]; gather at layer l reads
// A[(l-1)%3] for rows touched at l-1 (value = A/hc), else persistent child[];
// k_msg(l) merges layer l-1 averages into child[] (row-disjoint from its own
// fallback reads) and clears A[(l+1)%3] rows for layer l+1 (buffer free since
// its last reader was k_msg(l-1), ordered by the launch boundary).
// ---------------------------------------------------------------------------
constexpr size_t N_CHILD  = (size_t)BS_ * DEP_;              // 2,097,152
constexpr size_t OFF_A0   = N_CHILD;
constexpr size_t OFF_WT   = N_CHILD * 4;                     // after child+A0..A2
constexpr size_t N_WT     = (size_t)R_ * FEAT_ * DEP_;       // 1,024,000
constexpr size_t OFF_SORT = OFF_WT + N_WT;
constexpr size_t N_SORT   = (size_t)L_ * NEDGE_;             // 65,536
constexpr size_t OFF_CHUNK= OFF_SORT + N_SORT;
constexpr size_t N_CHUNK_I= (size_t)L_ * NCH_ * 4;           // 20,480 int4 -> 81,920 ints
constexpr size_t OFF_HC   = OFF_CHUNK + N_CHUNK_I;
constexpr size_t N_HC     = (size_t)(L_ + 1) * BS_;          // 557,056 ints

// ---------------------------------------------------------------------------
// K_PRE: one launch does everything child-independent.
// Blocks 0..15: per-layer relation binning + chunk table + head-count hist.
// Blocks 16..: W re-layout to WT2[r][i4][k][c] + zero child+A0 + zero hc[L].
// ---------------------------------------------------------------------------
__global__ void k_pre(const float* __restrict__ W, const int* __restrict__ rels,
                      const int* __restrict__ heads,
                      float* __restrict__ WT2, int* __restrict__ sorted,
                      int4* __restrict__ chunks, int* __restrict__ hc,
                      float* __restrict__ zero_base) {
  int blk = blockIdx.x, tid = threadIdx.x;
  if (blk < L_) {
    int l = blk;
    __shared__ int hist[R_], startA[R_], rank[R_], cstart[R_];
    __shared__ int ntot;
    if (tid < R_) { hist[tid] = 0; rank[tid] = 0; }
    int* hcl = hc + (size_t)l * BS_;
    for (int i = tid; i < BS_; i += 256) hcl[i] = 0;
    __syncthreads();
    for (int ed = tid; ed < NEDGE_; ed += 256) {
      int b = ed >> 7, e = ed & (E_ - 1);
      atomicAdd(&hist[rels[(b * L_ + l) * E_ + e]], 1);
      atomicAdd(&hcl[b * S_ + heads[(b * L_ + l) * E_ + e]], 1);
    }
    __syncthreads();
    if (tid == 0) {
      int s = 0, cs = 0;
      for (int r = 0; r < R_; ++r) {
        startA[r] = s; s += hist[r];
        cstart[r] = cs; cs += (hist[r] + CH_ - 1) / CH_;
      }
      ntot = cs;
    }
    __syncthreads();
    for (int ed = tid; ed < NEDGE_; ed += 256) {
      int b = ed >> 7, e = ed & (E_ - 1);
      int r = rels[(b * L_ + l) * E_ + e];
      int pos = startA[r] + atomicAdd(&rank[r], 1);
      sorted[l * NEDGE_ + pos] = ed;
    }
    if (tid < R_) {
      int n = hist[tid], st = startA[tid], cs = cstart[tid];
      for (int m = 0; m * CH_ < n; ++m) {
        int c = n - m * CH_; if (c > CH_) c = CH_;
        chunks[l * NCH_ + cs + m] = make_int4(tid, st + m * CH_, c, 0);
      }
    }
    __syncthreads();
    for (int i = ntot + tid; i < NCH_; i += 256)
      chunks[l * NCH_ + i] = make_int4(0, 0, 0, 0);
  } else {
    int gtid = (blk - L_) * 256 + tid;
    const int NT = PREB_ * 256;
    // W [R][k=DEP][d=FEAT] -> WT2 [r][i4=d/4][k][c=d%4]
    for (int gid = gtid; gid < (int)N_WT; gid += NT) {
      int r = gid / 20480;           // 80*64*4
      int rem = gid - r * 20480;
      int i4 = rem >> 8;
      int k = (rem >> 2) & 63;
      int c = rem & 3;
      WT2[gid] = W[((size_t)r * DEP_ + k) * FEAT_ + 4 * i4 + c];
    }
    // zero child + A0 (contiguous) with float4
    float4* z4 = (float4*)zero_base;
    int nz4 = (int)((N_CHILD * 2) / 4);
    for (int i = gtid; i < nz4; i += NT) z4[i] = make_float4(0.f, 0.f, 0.f, 0.f);
    // zero hc dummy ("layer -1")
    int* hcd = hc + (size_t)L_ * BS_;
    for (int i = gtid; i < BS_; i += NT) hcd[i] = 0;
  }
}

// ---------------------------------------------------------------------------
// K_M: per-layer fat kernel. Phase 1: merge layer l-1 averages into child[].
// Phase 2: clear A_next rows for layer l+1. Phase 3: relation-chunk matvecs
// with lazy child resolution, atomic scatter into A_cur.
// Phases are mutually race-free (see layout comment); no internal grid sync.
// ---------------------------------------------------------------------------
__global__ void __launch_bounds__(320) k_msg(
    const float* __restrict__ context, const float* __restrict__ WT2,
    const int* __restrict__ heads, const int* __restrict__ tails,
    float* __restrict__ child, const int* __restrict__ sorted,
    const int4* __restrict__ chunks, const int* __restrict__ hc, int l,
    const float* __restrict__ Aprev, float* __restrict__ Acur,
    float* __restrict__ Anext) {
  int tid = threadIdx.x;
  int gtid = blockIdx.x * 320 + tid;
  const int NT = NCH_ * 320;

  // Phase 1: merge layer l-1 (rows touched at l-1; duplicate writes identical)
  if (l > 0) {
    const int* hcp = hc + (size_t)(l - 1) * BS_;
    for (int idx = gtid; idx < NEDGE_ * DEP_; idx += NT) {
      int ed = idx >> 6, k = idx & 63;
      int b = ed >> 7, e = ed & (E_ - 1);
      int row = b * S_ + heads[(b * L_ + (l - 1)) * E_ + e];
      float c = (float)hcp[row];   // >= 1 (row is a head of layer l-1)
      child[(size_t)row * DEP_ + k] = Aprev[(size_t)row * DEP_ + k] / c;
    }
  }
  // Phase 2: clear next layer's accumulator rows
  if (l + 1 < L_) {
    for (int idx = gtid; idx < NEDGE_ * DEP_; idx += NT) {
      int ed = idx >> 6, k = idx & 63;
      int b = ed >> 7, e = ed & (E_ - 1);
      int row = b * S_ + heads[(b * L_ + (l + 1)) * E_ + e];
      Anext[(size_t)row * DEP_ + k] = 0.f;
    }
  }

  // Phase 3: chunk compute
  int4 ck = chunks[l * NCH_ + blockIdx.x];
  int r = ck.x, start = ck.y, ccnt = ck.z;
  if (ccnt == 0) return;
  int s = tid >> 6;     // wave / d-slice
  int k = tid & 63;     // lane / output row

  __shared__ int eids[CH_], ts_[CH_], touched[CH_];
  __shared__ float invp[CH_];
  __shared__ float feat[CH_][FEAT_];            // 20 KB
  __shared__ float part[NSLICE_][CH_][DEP_];    // 20 KB
  const int* hcprev = hc + (size_t)((l == 0) ? L_ : (l - 1)) * BS_;
  if (tid < ccnt) {
    int ed = sorted[l * NEDGE_ + start + tid];
    eids[tid] = ed;
    int b = ed >> 7, e = ed & (E_ - 1);
    int t = tails[(b * L_ + l) * E_ + e];
    ts_[tid] = t;
    int cv = hcprev[b * S_ + t];
    touched[tid] = (cv > 0);
    invp[tid] = 1.0f / (float)(cv > 0 ? cv : 1);
  }
  __syncthreads();

  // W register cache: w[i].{x..w} = W[r][k][64s+4i+{0..3}], coalesced dwordx4
  const float4* Wp = (const float4*)WT2 + ((size_t)r * 80 + s * 16) * 64 + k;
  float4 w[16];
#pragma unroll
  for (int i = 0; i < 16; ++i) w[i] = Wp[(size_t)i * 64];

  // Stage feats with lazy child resolution
  for (int j = 0; j < ccnt; ++j) {
    int b = eids[j] >> 7;
    size_t row = (size_t)b * S_ + ts_[j];
    float v;
    if (tid < NODE_) {
      v = context[row * NODE_ + tid];
    } else {
      int k2 = tid - NODE_;
      v = touched[j] ? Aprev[row * DEP_ + k2] * invp[j]
                     : child[row * DEP_ + k2];
    }
    feat[j][tid] = v;
  }
  __syncthreads();

  for (int j = 0; j < ccnt; ++j) {
    const float4* f4 = (const float4*)&feat[j][s * 64];   // LDS broadcasts
    float a0 = 0.f, a1 = 0.f, a2 = 0.f, a3 = 0.f;
#pragma unroll
    for (int i = 0; i < 16; ++i) {
      float4 f = f4[i];
      a0 = fmaf(w[i].x, f.x, a0);
      a1 = fmaf(w[i].y, f.y, a1);
      a2 = fmaf(w[i].z, f.z, a2);
      a3 = fmaf(w[i].w, f.w, a3);
    }
    part[s][j][k] = (a0 + a1) + (a2 + a3);
  }
  __syncthreads();

  for (int idx = tid; idx < ccnt * DEP_; idx += 320) {
    int j = idx >> 6, k2 = idx & 63;
    float m = part[0][j][k2] + part[1][j][k2] + part[2][j][k2] +
              part[3][j][k2] + part[4][j][k2];
    int ed = eids[j];
    int b = ed >> 7, e = ed & (E_ - 1);
    int h = heads[(b * L_ + l) * E_ + e];
    atomicAdd(&Acur[((size_t)b * S_ + h) * DEP_ + k2], m);
  }
}

// ---------------------------------------------------------------------------
// K_O: out = concat(context, childval) with the layer-15 merge applied lazily.
// ---------------------------------------------------------------------------
__global__ void k_out(const float4* __restrict__ ctx4,
                      const float4* __restrict__ chd4,
                      const float4* __restrict__ A4,     // A[15%3] = A0
                      const int* __restrict__ hc15,
                      float4* __restrict__ out4) {
  constexpr int TOT4 = B_ * S_ * (FEAT_ / 4);
  int i = blockIdx.x * blockDim.x + threadIdx.x;
  if (i >= TOT4) return;
  int row = i / 80;
  int c4 = i - row * 80;
  float4 v;
  if (c4 < 64) {
    v = ctx4[(size_t)row * 64 + c4];
  } else {
    int k4 = c4 - 64;
    int cv = hc15[row];
    if (cv > 0) {
      float inv = 1.0f / (float)cv;
      float4 a = A4[(size_t)row * 16 + k4];
      v = make_float4(a.x * inv, a.y * inv, a.z * inv, a.w * inv);
    } else {
      v = chd4[(size_t)row * 16 + k4];
    }
  }
  out4[i] = v;
}

extern "C" void kernel_launch(void* const* d_in, const int* in_sizes, int n_in,
                              void* d_out, int out_size, void* d_ws, size_t ws_size,
                              hipStream_t stream) {
  const float* context = (const float*)d_in[0];
  const float* dep_W   = (const float*)d_in[1];
  const int*   heads   = (const int*)d_in[2];
  const int*   tails   = (const int*)d_in[3];
  const int*   rels    = (const int*)d_in[4];
  float* out = (float*)d_out;

  float* ws = (float*)d_ws;
  float* child  = ws;
  float* A[3] = { ws + OFF_A0, ws + OFF_A0 + N_CHILD, ws + OFF_A0 + 2 * N_CHILD };
  float* WT2    = ws + OFF_WT;
  int*   sorted = (int*)(ws + OFF_SORT);
  int4*  chunks = (int4*)(ws + OFF_CHUNK);
  int*   hc     = (int*)(ws + OFF_HC);

  // One prepass launch: bin+hist (blocks 0..15), transpose+zero (rest).
  k_pre<<<L_ + PREB_, 256, 0, stream>>>(dep_W, rels, heads, WT2, sorted,
                                        chunks, hc, child);

  for (int l = 0; l < L_; ++l) {
    float* Acur  = A[l % 3];
    float* Aprev = A[(l + 2) % 3];   // == (l-1)%3; unread at l=0 (touched==0)
    float* Anext = A[(l + 1) % 3];
    k_msg<<<NCH_, 320, 0, stream>>>(context, WT2, heads, tails, child,
                                    sorted, chunks, hc, l, Aprev, Acur, Anext);
  }

  constexpr int TOT4 = B_ * S_ * (FEAT_ / 4);
  k_out<<<(TOT4 + 255) / 256, 256, 0, stream>>>(
      (const float4*)context, (const float4*)child, (const float4*)A[0],
      hc + (size_t)(L_ - 1) * BS_, (float4*)out);
}

// Round 5
// 399.939 us; speedup vs baseline: 1.6938x; 1.6938x over previous
//
#include <hip/hip_runtime.h>

// Problem constants: B,S,NODE,DEP,R,L,E = 32,1024,256,64,50,16,128
constexpr int B_ = 32;
constexpr int S_ = 1024;
constexpr int NODE_ = 256;
constexpr int DEP_ = 64;
constexpr int R_ = 50;
constexpr int L_ = 16;
constexpr int E_ = 128;
constexpr int FEAT_ = NODE_ + DEP_;     // 320
constexpr int NEDGE_ = B_ * E_;         // 4096 edges per layer
constexpr int BS_ = B_ * S_;            // 32768 rows
constexpr int CH_ = 16;                 // edges per relation-chunk
constexpr int NCH_ = 320;               // sum ceil(n_r/16) <= 256+50 = 306
constexpr int PREB_ = 512;              // worker blocks in k_pre

// ---------------------------------------------------------------------------
// Workspace (floats unless noted):
//  child[BS*64] | A0|A1|A2 (BS*64 each) | WT2 | sorted(int) | chunks(int4) |
//  hc[(L+1)*BS] (int; hc[L] = all-zero dummy = "layer -1")
// Layer l scatters into A[l%3]; a tail at layer l resolves lazily:
//   touched@l-1 ? A[(l-1)%3]/hc[l-1] : child[].   k_msg(l) ALSO (after its
// compute) merges layer l-1 averages into child[] (row-disjoint from its own
// fallback reads) and clears A[(l+1)%3] rows for layer l+1.
// ---------------------------------------------------------------------------
constexpr size_t N_CHILD  = (size_t)BS_ * DEP_;              // 2,097,152
constexpr size_t OFF_A0   = N_CHILD;
constexpr size_t OFF_WT   = N_CHILD * 4;
constexpr size_t N_WT     = (size_t)R_ * FEAT_ * DEP_;       // 1,024,000
constexpr size_t OFF_SORT = OFF_WT + N_WT;
constexpr size_t N_SORT   = (size_t)L_ * NEDGE_;
constexpr size_t OFF_CHUNK= OFF_SORT + N_SORT;
constexpr size_t N_CHUNK_I= (size_t)L_ * NCH_ * 4;
constexpr size_t OFF_HC   = OFF_CHUNK + N_CHUNK_I;

// ---------------------------------------------------------------------------
// K_PRE: blocks 0..15 = per-layer binning + chunk table + head-count hist;
// blocks 16.. = W re-layout to WT2[r][i4][k][c] + zero child+A0 + zero hc[L].
// ---------------------------------------------------------------------------
__global__ void k_pre(const float* __restrict__ W, const int* __restrict__ rels,
                      const int* __restrict__ heads,
                      float* __restrict__ WT2, int* __restrict__ sorted,
                      int4* __restrict__ chunks, int* __restrict__ hc,
                      float* __restrict__ zero_base) {
  int blk = blockIdx.x, tid = threadIdx.x;
  if (blk < L_) {
    int l = blk;
    __shared__ int hist[R_], startA[R_], rank[R_], cstart[R_];
    __shared__ int ntot;
    if (tid < R_) { hist[tid] = 0; rank[tid] = 0; }
    int* hcl = hc + (size_t)l * BS_;
    for (int i = tid; i < BS_; i += 256) hcl[i] = 0;
    __syncthreads();
    for (int ed = tid; ed < NEDGE_; ed += 256) {
      int b = ed >> 7, e = ed & (E_ - 1);
      atomicAdd(&hist[rels[(b * L_ + l) * E_ + e]], 1);
      atomicAdd(&hcl[b * S_ + heads[(b * L_ + l) * E_ + e]], 1);
    }
    __syncthreads();
    if (tid == 0) {
      int s = 0, cs = 0;
      for (int r = 0; r < R_; ++r) {
        startA[r] = s; s += hist[r];
        cstart[r] = cs; cs += (hist[r] + CH_ - 1) / CH_;
      }
      ntot = cs;
    }
    __syncthreads();
    for (int ed = tid; ed < NEDGE_; ed += 256) {
      int b = ed >> 7, e = ed & (E_ - 1);
      int r = rels[(b * L_ + l) * E_ + e];
      int pos = startA[r] + atomicAdd(&rank[r], 1);
      sorted[l * NEDGE_ + pos] = ed;
    }
    if (tid < R_) {
      int n = hist[tid], st = startA[tid], cs = cstart[tid];
      for (int m = 0; m * CH_ < n; ++m) {
        int c = n - m * CH_; if (c > CH_) c = CH_;
        chunks[l * NCH_ + cs + m] = make_int4(tid, st + m * CH_, c, 0);
      }
    }
    __syncthreads();
    for (int i = ntot + tid; i < NCH_; i += 256)
      chunks[l * NCH_ + i] = make_int4(0, 0, 0, 0);
  } else {
    int gtid = (blk - L_) * 256 + tid;
    const int NT = PREB_ * 256;
    for (int gid = gtid; gid < (int)N_WT; gid += NT) {
      int r = gid / 20480;           // 80*64*4
      int rem = gid - r * 20480;
      int i4 = rem >> 8;
      int k = (rem >> 2) & 63;
      int c = rem & 3;
      WT2[gid] = W[((size_t)r * DEP_ + k) * FEAT_ + 4 * i4 + c];
    }
    float4* z4 = (float4*)zero_base;
    int nz4 = (int)((N_CHILD * 2) / 4);
    for (int i = gtid; i < nz4; i += NT) z4[i] = make_float4(0.f, 0.f, 0.f, 0.f);
    int* hcd = hc + (size_t)L_ * BS_;
    for (int i = gtid; i < BS_; i += NT) hcd[i] = 0;
  }
}

__device__ __forceinline__ float dot64(const float4* __restrict__ f4,
                                       const float4* __restrict__ w) {
  float a0 = 0.f, a1 = 0.f, a2 = 0.f, a3 = 0.f;
#pragma unroll
  for (int i = 0; i < 16; ++i) {
    float4 f = f4[i];
    a0 = fmaf(w[i].x, f.x, a0);
    a1 = fmaf(w[i].y, f.y, a1);
    a2 = fmaf(w[i].z, f.z, a2);
    a3 = fmaf(w[i].w, f.w, a3);
  }
  return (a0 + a1) + (a2 + a3);
}

// ---------------------------------------------------------------------------
// K_M v5: per-layer kernel. Compute section: uniform scalar-load metadata
// prefetch -> 16 pipelined feat gathers -> LDS stage -> per-wave 64-d dots ->
// direct atomic scatter (no part-combine). Then (off the critical path)
// merge layer l-1 into child[] and clear A_next rows for layer l+1.
// ---------------------------------------------------------------------------
__global__ void __launch_bounds__(320) k_msg(
    const float* __restrict__ context, const float* __restrict__ WT2,
    const int* __restrict__ heads, const int* __restrict__ tails,
    float* __restrict__ child, const int* __restrict__ sorted,
    const int4* __restrict__ chunks, const int* __restrict__ hc, int l,
    const float* __restrict__ Aprev, float* __restrict__ Acur,
    float* __restrict__ Anext) {
  int tid = threadIdx.x;
  const int4 ck = chunks[l * NCH_ + blockIdx.x];     // uniform -> s_load
  const int r = ck.x, start = ck.y, ccnt = ck.z;

  __shared__ float feat[CH_][FEAT_];                 // 20 KB

  if (ccnt > 0) {
    int s = tid >> 6;        // wave / d-slice 0..4
    int k = tid & 63;        // lane / output row

    // --- uniform metadata prefetch (3 pipelined scalar-load rounds) ---
    int edv[CH_], tsv[CH_], hv[CH_], tch[CH_];
    float scl[CH_];
#pragma unroll
    for (int j = 0; j < CH_; ++j) {
      int jj = (j < ccnt) ? j : (ccnt - 1);
      edv[j] = sorted[l * NEDGE_ + start + jj];
    }
#pragma unroll
    for (int j = 0; j < CH_; ++j) {
      int b = edv[j] >> 7, e = edv[j] & (E_ - 1);
      tsv[j] = tails[(b * L_ + l) * E_ + e];
      hv[j]  = heads[(b * L_ + l) * E_ + e];
    }
    const int* hcprev = hc + (size_t)((l == 0) ? L_ : (l - 1)) * BS_;
#pragma unroll
    for (int j = 0; j < CH_; ++j) {
      int b = edv[j] >> 7;
      int cv = hcprev[b * S_ + tsv[j]];
      tch[j] = (cv > 0);
      scl[j] = (cv > 0) ? 1.0f / (float)cv : 1.0f;
    }

    // --- issue all 16 feat gathers back-to-back (independent) ---
    float v[CH_];
    if (s < 4) {
#pragma unroll
      for (int j = 0; j < CH_; ++j) {
        size_t row = (size_t)(edv[j] >> 7) * S_ + tsv[j];
        v[j] = context[row * NODE_ + tid];
      }
    } else {
      int k2 = tid - NODE_;
#pragma unroll
      for (int j = 0; j < CH_; ++j) {
        size_t row = (size_t)(edv[j] >> 7) * S_ + tsv[j];
        const float* p = tch[j] ? Aprev : child;   // uniform pointer select
        v[j] = p[row * DEP_ + k2] * scl[j];        // scl==1 when untouched
      }
    }

    // --- W register cache (16 coalesced dwordx4, stride 1 KB, L2-hot) ---
    const float4* Wp = (const float4*)WT2 + ((size_t)r * 80 + s * 16) * 64 + k;
    float4 w[16];
#pragma unroll
    for (int i = 0; i < 16; ++i) w[i] = Wp[(size_t)i * 64];

    // --- stage feats ---
#pragma unroll
    for (int j = 0; j < CH_; ++j) feat[j][tid] = v[j];
    __syncthreads();

    // --- per-wave 64-d dots + direct atomic scatter ---
    if (ccnt == CH_) {
#pragma unroll 4
      for (int j = 0; j < CH_; ++j) {
        float d = dot64((const float4*)&feat[j][s * 64], w);
        size_t row = (size_t)(edv[j] >> 7) * S_ + hv[j];
        atomicAdd(&Acur[row * DEP_ + k], d);
      }
    } else {
      for (int j = 0; j < ccnt; ++j) {
        float d = dot64((const float4*)&feat[j][s * 64], w);
        size_t row = (size_t)(edv[j] >> 7) * S_ + hv[j];
        atomicAdd(&Acur[row * DEP_ + k], d);
      }
    }
  }

  // --- deferred phases (row-disjoint from all concurrent reads above) ---
  int gtid = blockIdx.x * 320 + tid;
  const int NT = NCH_ * 320;
  if (l > 0) {
    const int* hcp = hc + (size_t)(l - 1) * BS_;
    for (int idx = gtid; idx < NEDGE_ * DEP_; idx += NT) {
      int ed = idx >> 6, k = idx & 63;
      int b = ed >> 7, e = ed & (E_ - 1);
      int row = b * S_ + heads[(b * L_ + (l - 1)) * E_ + e];
      float c = (float)hcp[row];   // >= 1
      child[(size_t)row * DEP_ + k] = Aprev[(size_t)row * DEP_ + k] / c;
    }
  }
  if (l + 1 < L_) {
    for (int idx = gtid; idx < NEDGE_ * DEP_; idx += NT) {
      int ed = idx >> 6, k = idx & 63;
      int b = ed >> 7, e = ed & (E_ - 1);
      int row = b * S_ + heads[(b * L_ + (l + 1)) * E_ + e];
      Anext[(size_t)row * DEP_ + k] = 0.f;
    }
  }
}

// ---------------------------------------------------------------------------
// K_O: out = concat(context, child) with the layer-15 merge applied lazily.
// ---------------------------------------------------------------------------
__global__ void k_out(const float4* __restrict__ ctx4,
                      const float4* __restrict__ chd4,
                      const float4* __restrict__ A4,     // A[15%3] = A0
                      const int* __restrict__ hc15,
                      float4* __restrict__ out4) {
  constexpr int TOT4 = B_ * S_ * (FEAT_ / 4);
  int i = blockIdx.x * blockDim.x + threadIdx.x;
  if (i >= TOT4) return;
  int row = i / 80;
  int c4 = i - row * 80;
  float4 v;
  if (c4 < 64) {
    v = ctx4[(size_t)row * 64 + c4];
  } else {
    int k4 = c4 - 64;
    int cv = hc15[row];
    if (cv > 0) {
      float inv = 1.0f / (float)cv;
      float4 a = A4[(size_t)row * 16 + k4];
      v = make_float4(a.x * inv, a.y * inv, a.z * inv, a.w * inv);
    } else {
      v = chd4[(size_t)row * 16 + k4];
    }
  }
  out4[i] = v;
}

extern "C" void kernel_launch(void* const* d_in, const int* in_sizes, int n_in,
                              void* d_out, int out_size, void* d_ws, size_t ws_size,
                              hipStream_t stream) {
  const float* context = (const float*)d_in[0];
  const float* dep_W   = (const float*)d_in[1];
  const int*   heads   = (const int*)d_in[2];
  const int*   tails   = (const int*)d_in[3];
  const int*   rels    = (const int*)d_in[4];
  float* out = (float*)d_out;

  float* ws = (float*)d_ws;
  float* child  = ws;
  float* A[3] = { ws + OFF_A0, ws + OFF_A0 + N_CHILD, ws + OFF_A0 + 2 * N_CHILD };
  float* WT2    = ws + OFF_WT;
  int*   sorted = (int*)(ws + OFF_SORT);
  int4*  chunks = (int4*)(ws + OFF_CHUNK);
  int*   hc     = (int*)(ws + OFF_HC);

  k_pre<<<L_ + PREB_, 256, 0, stream>>>(dep_W, rels, heads, WT2, sorted,
                                        chunks, hc, child);

  for (int l = 0; l < L_; ++l) {
    float* Acur  = A[l % 3];
    float* Aprev = A[(l + 2) % 3];
    float* Anext = A[(l + 1) % 3];
    k_msg<<<NCH_, 320, 0, stream>>>(context, WT2, heads, tails, child,
                                    sorted, chunks, hc, l, Aprev, Acur, Anext);
  }

  constexpr int TOT4 = B_ * S_ * (FEAT_ / 4);
  k_out<<<(TOT4 + 255) / 256, 256, 0, stream>>>(
      (const float4*)context, (const float4*)child, (const float4*)A[0],
      hc + (size_t)(L_ - 1) * BS_, (float4*)out);
}

// Round 6
// 313.003 us; speedup vs baseline: 2.1643x; 1.2777x over previous
//
#include <hip/hip_runtime.h>

// Problem constants: B,S,NODE,DEP,R,L,E = 32,1024,256,64,50,16,128
constexpr int B_ = 32;
constexpr int S_ = 1024;
constexpr int NODE_ = 256;
constexpr int DEP_ = 64;
constexpr int R_ = 50;
constexpr int L_ = 16;
constexpr int E_ = 128;
constexpr int FEAT_ = NODE_ + DEP_;     // 320
constexpr int NEDGE_ = B_ * E_;         // 4096 edges per layer
constexpr int BS_ = B_ * S_;            // 32768 rows
constexpr int CH_ = 16;                 // edges per relation-chunk
constexpr int NCH_ = 320;               // sum ceil(n_r/16) <= 306
constexpr int PREB_ = 512;              // worker blocks in k_pre

// ---------------------------------------------------------------------------
// Key algebra: msg = W[r][:,0:256]@ctx[t] + W[r][:,256:320]@childval[t].
// The ctx term + all index-derived metadata are layer-chain-independent ->
// precomputed in k_ctx (fully parallel). Everything is pre-scaled by
// 1/cnt[head], so accumulators A[] hold AVERAGES directly: the per-layer
// "assignment" is a plain row copy, no division anywhere on the serial path.
// Triple-buffered A: layer l scatters into A[l%3]; tail rows touched at l-1
// resolve from A[(l-1)%3] (tch flag precomputed); else persistent child[].
// k_layer(l) also (race-free, row-disjoint) copies layer l-1 rows into
// child[] and zeroes A[(l+1)%3] rows for layer l+1.
// ---------------------------------------------------------------------------
constexpr size_t N_CHILD  = (size_t)BS_ * DEP_;              // 2,097,152 floats
constexpr size_t OFF_A0   = N_CHILD;                         // A0,A1,A2 follow
constexpr size_t OFF_WT   = N_CHILD * 4;
constexpr size_t N_WT     = (size_t)R_ * FEAT_ * DEP_;       // 1,024,000
constexpr size_t OFF_SORT = OFF_WT + N_WT;
constexpr size_t N_SORT   = (size_t)L_ * NEDGE_;             // 65,536 ints
constexpr size_t OFF_CHUNK= OFF_SORT + N_SORT;
constexpr size_t N_CHUNK_I= (size_t)L_ * NCH_ * 4;           // ints
constexpr size_t OFF_HC   = OFF_CHUNK + N_CHUNK_I;
constexpr size_t N_HC     = (size_t)L_ * BS_;                // 524,288 ints
constexpr size_t OFF_MT   = OFF_HC + N_HC;                   // m_trow (tch in sign)
constexpr size_t OFF_MH   = OFF_MT + N_SORT;                 // m_hrow
constexpr size_t OFF_MI   = OFF_MH + N_SORT;                 // m_invc
constexpr size_t OFF_CD   = OFF_MI + N_SORT;                 // ctxdot
constexpr size_t N_CD     = (size_t)L_ * NEDGE_ * DEP_;      // 4,194,304

// ---------------------------------------------------------------------------
// K_PRE: blocks 0..15 = per-layer relation binning + chunk table + head-count
// hist; blocks 16.. = W re-layout WT2[r][i4][k][c] + zero child+A0.
// ---------------------------------------------------------------------------
__global__ void k_pre(const float* __restrict__ W, const int* __restrict__ rels,
                      const int* __restrict__ heads,
                      float* __restrict__ WT2, int* __restrict__ sorted,
                      int4* __restrict__ chunks, int* __restrict__ hc,
                      float* __restrict__ zero_base) {
  int blk = blockIdx.x, tid = threadIdx.x;
  if (blk < L_) {
    int l = blk;
    __shared__ int hist[R_], startA[R_], rank[R_], cstart[R_];
    __shared__ int ntot;
    if (tid < R_) { hist[tid] = 0; rank[tid] = 0; }
    int* hcl = hc + (size_t)l * BS_;
    for (int i = tid; i < BS_; i += 256) hcl[i] = 0;
    __syncthreads();
    for (int ed = tid; ed < NEDGE_; ed += 256) {
      int b = ed >> 7, e = ed & (E_ - 1);
      atomicAdd(&hist[rels[(b * L_ + l) * E_ + e]], 1);
      atomicAdd(&hcl[b * S_ + heads[(b * L_ + l) * E_ + e]], 1);
    }
    __syncthreads();
    if (tid == 0) {
      int s = 0, cs = 0;
      for (int r = 0; r < R_; ++r) {
        startA[r] = s; s += hist[r];
        cstart[r] = cs; cs += (hist[r] + CH_ - 1) / CH_;
      }
      ntot = cs;
    }
    __syncthreads();
    for (int ed = tid; ed < NEDGE_; ed += 256) {
      int b = ed >> 7, e = ed & (E_ - 1);
      int r = rels[(b * L_ + l) * E_ + e];
      int pos = startA[r] + atomicAdd(&rank[r], 1);
      sorted[l * NEDGE_ + pos] = ed;
    }
    if (tid < R_) {
      int n = hist[tid], st = startA[tid], cs = cstart[tid];
      for (int m = 0; m * CH_ < n; ++m) {
        int c = n - m * CH_; if (c > CH_) c = CH_;
        chunks[l * NCH_ + cs + m] = make_int4(tid, st + m * CH_, c, 0);
      }
    }
    __syncthreads();
    for (int i = ntot + tid; i < NCH_; i += 256)
      chunks[l * NCH_ + i] = make_int4(0, 0, 0, 0);
  } else {
    int gtid = (blk - L_) * 256 + tid;
    const int NT = PREB_ * 256;
    for (int gid = gtid; gid < (int)N_WT; gid += NT) {
      int r = gid / 20480;           // 80*64*4
      int rem = gid - r * 20480;
      int i4 = rem >> 8;
      int k = (rem >> 2) & 63;
      int c = rem & 3;
      WT2[gid] = W[((size_t)r * DEP_ + k) * FEAT_ + 4 * i4 + c];
    }
    float4* z4 = (float4*)zero_base;          // child + A0, contiguous
    int nz4 = (int)((N_CHILD * 2) / 4);
    for (int i = gtid; i < nz4; i += NT) z4[i] = make_float4(0.f, 0.f, 0.f, 0.f);
  }
}

__device__ __forceinline__ float dot64(const float4* __restrict__ f4,
                                       const float4* __restrict__ w) {
  float a0 = 0.f, a1 = 0.f, a2 = 0.f, a3 = 0.f;
#pragma unroll
  for (int i = 0; i < 16; ++i) {
    float4 f = f4[i];
    a0 = fmaf(w[i].x, f.x, a0);
    a1 = fmaf(w[i].y, f.y, a1);
    a2 = fmaf(w[i].z, f.z, a2);
    a3 = fmaf(w[i].w, f.w, a3);
  }
  return (a0 + a1) + (a2 + a3);
}

// ---------------------------------------------------------------------------
// K_CTX: fully parallel precompute over all L*NEDGE edge-slots.
//  - per-slot metadata: m_trow (tail row | touched<<31), m_hrow, m_invc
//  - ctxdot[pos][k] = (W[r][k][0:256] . ctx[tail]) * invcnt[head]
// One block (256 thr = 4 waves) per relation-chunk; wave s owns d-slice
// [64s,64s+64); partials combined via LDS.
// ---------------------------------------------------------------------------
__global__ void __launch_bounds__(256) k_ctx(
    const float* __restrict__ context, const float* __restrict__ WT2,
    const int* __restrict__ heads, const int* __restrict__ tails,
    const int* __restrict__ sorted, const int4* __restrict__ chunks,
    const int* __restrict__ hc, float* __restrict__ ctxdot,
    int* __restrict__ m_trow, int* __restrict__ m_hrow,
    float* __restrict__ m_invc) {
  int cid = blockIdx.x;
  int l = cid / NCH_;
  int4 ck = chunks[cid];
  int r = ck.x, start = ck.y, ccnt = ck.z;
  if (ccnt == 0) return;
  int tid = threadIdx.x, s = tid >> 6, k = tid & 63;

  __shared__ float feat[CH_][NODE_];         // 16 KB
  __shared__ float part[4][CH_][DEP_];       // 16 KB
  __shared__ int trows[CH_];
  __shared__ float invs[CH_];

  if (tid < ccnt) {
    int pos = l * NEDGE_ + start + tid;
    int ed = sorted[pos];
    int b = ed >> 7, e = ed & (E_ - 1);
    int t = tails[(b * L_ + l) * E_ + e];
    int h = heads[(b * L_ + l) * E_ + e];
    int trow = b * S_ + t, hrow = b * S_ + h;
    int tch = (l > 0) && (hc[(size_t)(l - 1) * BS_ + trow] > 0);
    float invc = 1.0f / (float)hc[(size_t)l * BS_ + hrow];   // >= 1
    m_trow[pos] = trow | (tch ? (int)0x80000000 : 0);
    m_hrow[pos] = hrow;
    m_invc[pos] = invc;
    trows[tid] = trow;
    invs[tid] = invc;
  }
  __syncthreads();

  int tr[CH_];
#pragma unroll
  for (int j = 0; j < CH_; ++j) tr[j] = trows[(j < ccnt) ? j : (ccnt - 1)];

  // W ctx-slice register cache (coalesced dwordx4)
  const float4* Wp = (const float4*)WT2 + ((size_t)r * 80 + s * 16) * 64 + k;
  float4 w[16];
#pragma unroll
  for (int i = 0; i < 16; ++i) w[i] = Wp[(size_t)i * 64];

  // 16 independent coalesced ctx-row gathers
#pragma unroll
  for (int j = 0; j < CH_; ++j)
    feat[j][tid] = context[(size_t)tr[j] * NODE_ + tid];
  __syncthreads();

  for (int j = 0; j < ccnt; ++j)
    part[s][j][k] = dot64((const float4*)&feat[j][s * 64], w);
  __syncthreads();

  for (int idx = tid; idx < ccnt * DEP_; idx += 256) {
    int j = idx >> 6, k2 = idx & 63;
    ctxdot[(size_t)(l * NEDGE_ + start + j) * DEP_ + k2] =
        (part[0][j][k2] + part[1][j][k2] + part[2][j][k2] + part[3][j][k2]) *
        invs[j];
  }
}

// ---------------------------------------------------------------------------
// K_LAYER: the only serial-chain kernel. Per chunk (<=16 edges, shared r):
// 4 waves; wave w handles edges j = w+4u. Gather 64-float child rows (lazy:
// A_prev if touched@l-1 else child), wave-local LDS stage, 64-wide dot,
// add precomputed ctxdot, atomic scatter of the pre-scaled contribution.
// Then: copy layer l-1 rows A_prev->child, zero A_next rows for l+1.
// ---------------------------------------------------------------------------
__global__ void __launch_bounds__(256) k_layer(
    const float* __restrict__ WT2, float* __restrict__ child,
    const int4* __restrict__ chunks, const int* __restrict__ m_trow,
    const int* __restrict__ m_hrow, const float* __restrict__ m_invc,
    const float* __restrict__ ctxdot, int l,
    const float* __restrict__ Aprev, float* __restrict__ Acur,
    float* __restrict__ Anext) {
  int tid = threadIdx.x;
  int4 ck = chunks[l * NCH_ + blockIdx.x];
  int r = ck.x, start = ck.y, ccnt = ck.z;
  __shared__ float feat[CH_][DEP_];          // 4 KB

  if (ccnt > 0) {
    int wv = tid >> 6, k = tid & 63;

    // W child-slice register cache (i4 = 64..79)
    const float4* Wp = (const float4*)WT2 + ((size_t)r * 80 + 64) * 64 + k;
    float4 w[16];
#pragma unroll
    for (int i = 0; i < 16; ++i) w[i] = Wp[(size_t)i * 64];

    int jj[4], valid[4], tch[4], trow[4], hrow[4];
    float invc[4];
#pragma unroll
    for (int u = 0; u < 4; ++u) {
      int j = wv + 4 * u;
      valid[u] = (j < ccnt);
      jj[u] = valid[u] ? j : (ccnt - 1);
      int pos = l * NEDGE_ + start + jj[u];
      int tr = m_trow[pos];
      tch[u] = (tr < 0);
      trow[u] = tr & 0x7fffffff;
      hrow[u] = m_hrow[pos];
      invc[u] = m_invc[pos];
    }

    float v[4];
#pragma unroll
    for (int u = 0; u < 4; ++u) {
      const float* p = tch[u] ? Aprev : child;   // A holds averages already
      v[u] = p[(size_t)trow[u] * DEP_ + k];
    }
#pragma unroll
    for (int u = 0; u < 4; ++u) feat[jj[u]][k] = v[u];
    __syncthreads();

#pragma unroll
    for (int u = 0; u < 4; ++u) {
      float d = dot64((const float4*)&feat[jj[u]][0], w);
      int pos = l * NEDGE_ + start + jj[u];
      float contrib = d * invc[u] + ctxdot[(size_t)pos * DEP_ + k];
      if (valid[u]) atomicAdd(&Acur[(size_t)hrow[u] * DEP_ + k], contrib);
    }
  }

  // Deferred row-disjoint phases
  int gtid = blockIdx.x * 256 + tid;
  const int NT = NCH_ * 256;
  if (l > 0) {
    const float4* Ap4 = (const float4*)Aprev;
    float4* ch4 = (float4*)child;
    const int* mh = m_hrow + (size_t)(l - 1) * NEDGE_;
    for (int idx = gtid; idx < NEDGE_ * 16; idx += NT) {
      int pos = idx >> 4, c4 = idx & 15;
      int hrow = mh[pos];
      ch4[(size_t)hrow * 16 + c4] = Ap4[(size_t)hrow * 16 + c4];
    }
  }
  if (l + 1 < L_) {
    float4* An4 = (float4*)Anext;
    const int* mh = m_hrow + (size_t)(l + 1) * NEDGE_;
    float4 z = make_float4(0.f, 0.f, 0.f, 0.f);
    for (int idx = gtid; idx < NEDGE_ * 16; idx += NT) {
      int pos = idx >> 4, c4 = idx & 15;
      An4[(size_t)mh[pos] * 16 + c4] = z;
    }
  }
}

// ---------------------------------------------------------------------------
// K_O: out = concat(context, childval); layer-15 rows read from A0 (averages).
// ---------------------------------------------------------------------------
__global__ void k_out(const float4* __restrict__ ctx4,
                      const float4* __restrict__ chd4,
                      const float4* __restrict__ A04,
                      const int* __restrict__ hc15,
                      float4* __restrict__ out4) {
  constexpr int TOT4 = B_ * S_ * (FEAT_ / 4);
  int i = blockIdx.x * blockDim.x + threadIdx.x;
  if (i >= TOT4) return;
  int row = i / 80;
  int c4 = i - row * 80;
  float4 v;
  if (c4 < 64) {
    v = ctx4[(size_t)row * 64 + c4];
  } else {
    int k4 = c4 - 64;
    v = (hc15[row] > 0) ? A04[(size_t)row * 16 + k4]
                        : chd4[(size_t)row * 16 + k4];
  }
  out4[i] = v;
}

extern "C" void kernel_launch(void* const* d_in, const int* in_sizes, int n_in,
                              void* d_out, int out_size, void* d_ws, size_t ws_size,
                              hipStream_t stream) {
  const float* context = (const float*)d_in[0];
  const float* dep_W   = (const float*)d_in[1];
  const int*   heads   = (const int*)d_in[2];
  const int*   tails   = (const int*)d_in[3];
  const int*   rels    = (const int*)d_in[4];
  float* out = (float*)d_out;

  float* ws = (float*)d_ws;
  float* child  = ws;
  float* A[3] = { ws + OFF_A0, ws + OFF_A0 + N_CHILD, ws + OFF_A0 + 2 * N_CHILD };
  float* WT2    = ws + OFF_WT;
  int*   sorted = (int*)(ws + OFF_SORT);
  int4*  chunks = (int4*)(ws + OFF_CHUNK);
  int*   hc     = (int*)(ws + OFF_HC);
  int*   m_trow = (int*)(ws + OFF_MT);
  int*   m_hrow = (int*)(ws + OFF_MH);
  float* m_invc = ws + OFF_MI;
  float* ctxdot = ws + OFF_CD;

  k_pre<<<L_ + PREB_, 256, 0, stream>>>(dep_W, rels, heads, WT2, sorted,
                                        chunks, hc, child);

  k_ctx<<<L_ * NCH_, 256, 0, stream>>>(context, WT2, heads, tails, sorted,
                                       chunks, hc, ctxdot, m_trow, m_hrow,
                                       m_invc);

  for (int l = 0; l < L_; ++l) {
    float* Acur  = A[l % 3];
    float* Aprev = A[(l + 2) % 3];
    float* Anext = A[(l + 1) % 3];
    k_layer<<<NCH_, 256, 0, stream>>>(WT2, child, chunks, m_trow, m_hrow,
                                      m_invc, ctxdot, l, Aprev, Acur, Anext);
  }

  constexpr int TOT4 = B_ * S_ * (FEAT_ / 4);
  k_out<<<(TOT4 + 255) / 256, 256, 0, stream>>>(
      (const float4*)context, (const float4*)child, (const float4*)A[0],
      hc + (size_t)(L_ - 1) * BS_, (float4*)out);
}